// Round 1
// baseline (738.497 us; speedup 1.0000x reference)
//
#include <hip/hip_runtime.h>

#define B_TOT 2048
#define M_SEQ 64
#define SDIM 32
#define CDIM 8
#define LDIM 128
#define HDIM 512

#define NROWS_NEXT (B_TOT * M_SEQ)       // 131072
#define NROWS_ALL  (NROWS_NEXT + B_TOT)  // 133120

typedef short bf16x8 __attribute__((ext_vector_type(8)));
typedef float f32x4  __attribute__((ext_vector_type(4)));

__device__ __forceinline__ unsigned short f2bf(float f) {
    unsigned int u = __builtin_bit_cast(unsigned int, f);
    u = u + 0x7FFFu + ((u >> 16) & 1u);   // round-to-nearest-even
    return (unsigned short)(u >> 16);
}

// XOR swizzle on LDS byte address: row = byte>>10 (1024B rows), flip bits 4-6
// with row&7. Bijective, 16B-segment preserving; used by ALL readers/writers.
__device__ __forceinline__ unsigned int swz(unsigned int byte) {
    return byte ^ (((byte >> 10) & 7u) << 4);
}

// ---------------------------------------------------------------------------
// Pack fp32 weight W[K][N] into bf16 fragment-major layout for 16x16x32 MFMA:
// out[((kt*(N/16) + nt)*64 + lane)*8 + j] = W[kt*32 + (lane>>4)*8 + j][nt*16 + (lane&15)]
// => each wave's B-fragment is one coalesced 16B/lane load.
// ---------------------------------------------------------------------------
__global__ void pack_weight(const float* __restrict__ W, short* __restrict__ out,
                            int K, int N) {
    int id = blockIdx.x * 256 + threadIdx.x;
    int total = K * N;
    if (id >= total) return;
    int j    = id & 7;
    int lane = (id >> 3) & 63;
    int tile = id >> 9;
    int NT   = N >> 4;
    int nt   = tile % NT;
    int kt   = tile / NT;
    int k = kt * 32 + ((lane >> 4) << 3) + j;
    int n = (nt << 4) + (lane & 15);
    out[id] = (short)f2bf(W[(size_t)k * N + n]);
}

// ---------------------------------------------------------------------------
// One MLP layer, 512 outputs, in-place in LDS. 8 waves; wave w owns ntiles
// [4w, 4w+4) x all 4 mtiles (16 output tiles, 64 acc VGPRs). K-loop reads the
// h-buffer, barrier, epilogue (bias+relu+bf16) overwrites it, barrier.
// ---------------------------------------------------------------------------
__device__ __forceinline__ void layer_lds(char* hbuf, const short* __restrict__ pw,
                                          const float* __restrict__ bias,
                                          int ktCount, int wave, int lane) {
    const int l15 = lane & 15;
    const int lhi = lane >> 4;
    f32x4 acc[4][4];
    #pragma unroll
    for (int mt = 0; mt < 4; ++mt)
        #pragma unroll
        for (int nt = 0; nt < 4; ++nt)
            acc[mt][nt] = (f32x4){0.f, 0.f, 0.f, 0.f};

    for (int kt = 0; kt < ktCount; ++kt) {
        bf16x8 a[4];
        #pragma unroll
        for (int mt = 0; mt < 4; ++mt) {
            unsigned int byte = (unsigned)((mt * 16 + l15) * 1024 + kt * 64 + (lhi << 4));
            a[mt] = *(const bf16x8*)(hbuf + swz(byte));
        }
        #pragma unroll
        for (int nt = 0; nt < 4; ++nt) {
            // pw index: (kt*32 + wave*4 + nt)*512 + lane*8   (NT=32 tiles)
            const bf16x8 b = *(const bf16x8*)(pw + ((size_t)(kt * 32 + wave * 4 + nt) << 9) + (lane << 3));
            #pragma unroll
            for (int mt = 0; mt < 4; ++mt)
                acc[mt][nt] = __builtin_amdgcn_mfma_f32_16x16x32_bf16(a[mt], b, acc[mt][nt], 0, 0, 0);
        }
    }
    __syncthreads();   // all reads of hbuf complete before in-place overwrite

    #pragma unroll
    for (int nt = 0; nt < 4; ++nt) {
        int colg = (wave * 4 + nt) * 16 + l15;
        float bv = bias[colg];
        #pragma unroll
        for (int mt = 0; mt < 4; ++mt) {
            #pragma unroll
            for (int r = 0; r < 4; ++r) {
                int row = mt * 16 + (lhi << 2) + r;
                float v = fmaxf(acc[mt][nt][r] + bv, 0.f);
                *(unsigned short*)(hbuf + swz((unsigned)(row * 1024 + colg * 2))) = f2bf(v);
            }
        }
    }
    __syncthreads();
}

// ---------------------------------------------------------------------------
// Fused encoder: rows [blk*64, blk*64+64). Blocks 0..2047 -> x_next rows
// (z -> z_target in d_out); blocks 2048..2079 -> x_k rows (z -> z_k ws).
// ---------------------------------------------------------------------------
__global__ __launch_bounds__(512) void encoder_kernel(
    const float* __restrict__ x_next, const float* __restrict__ x_k,
    const short* __restrict__ pw0, const short* __restrict__ pw1,
    const short* __restrict__ pw2, const short* __restrict__ pw3,
    const float* __restrict__ b0, const float* __restrict__ b1,
    const float* __restrict__ b2, const float* __restrict__ b3,
    float* __restrict__ z_target, float* __restrict__ z_k_out) {
    __shared__ __attribute__((aligned(16))) char hbuf[64 * 1024];
    const int tid  = threadIdx.x;
    const int wave = tid >> 6;
    const int lane = tid & 63;
    const int l15  = lane & 15;
    const int lhi  = lane >> 4;
    const int r0   = blockIdx.x * 64;

    const float* xin;
    float* zout;
    if (r0 < NROWS_NEXT) {
        xin  = x_next + (size_t)r0 * SDIM;
        zout = z_target + (size_t)r0 * LDIM;
    } else {
        xin  = x_k + (size_t)(r0 - NROWS_NEXT) * SDIM;
        zout = z_k_out + (size_t)(r0 - NROWS_NEXT) * LDIM;
    }

    // stage 64x32 fp32 -> bf16 into h cols [0,32)
    {
        int row = tid >> 3;
        int c   = (tid & 7) * 4;
        float4 v = *(const float4*)(xin + row * SDIM + c);
        uint2 p;
        p.x = (unsigned int)f2bf(v.x) | ((unsigned int)f2bf(v.y) << 16);
        p.y = (unsigned int)f2bf(v.z) | ((unsigned int)f2bf(v.w) << 16);
        *(uint2*)(hbuf + swz((unsigned)(row * 1024 + c * 2))) = p;
    }
    __syncthreads();

    layer_lds(hbuf, pw0, b0, 1, wave, lane);    // 32  -> 512, relu
    layer_lds(hbuf, pw1, b1, 16, wave, lane);   // 512 -> 512, relu
    layer_lds(hbuf, pw2, b2, 16, wave, lane);   // 512 -> 512, relu

    // layer 3: 512 -> 128, no relu, straight to global fp32. wave w owns ntile w.
    {
        f32x4 acc[4];
        #pragma unroll
        for (int mt = 0; mt < 4; ++mt) acc[mt] = (f32x4){0.f, 0.f, 0.f, 0.f};
        for (int kt = 0; kt < 16; ++kt) {
            bf16x8 a[4];
            #pragma unroll
            for (int mt = 0; mt < 4; ++mt) {
                unsigned int byte = (unsigned)((mt * 16 + l15) * 1024 + kt * 64 + (lhi << 4));
                a[mt] = *(const bf16x8*)(hbuf + swz(byte));
            }
            const bf16x8 b = *(const bf16x8*)(pw3 + ((size_t)(kt * 8 + wave) << 9) + (lane << 3));
            #pragma unroll
            for (int mt = 0; mt < 4; ++mt)
                acc[mt] = __builtin_amdgcn_mfma_f32_16x16x32_bf16(a[mt], b, acc[mt], 0, 0, 0);
        }
        int colg = wave * 16 + l15;
        float bv = b3[colg];
        #pragma unroll
        for (int mt = 0; mt < 4; ++mt) {
            #pragma unroll
            for (int r = 0; r < 4; ++r) {
                int row = mt * 16 + (lhi << 2) + r;
                zout[(size_t)row * LDIM + colg] = acc[mt][r] + bv;
            }
        }
    }
}

// ---------------------------------------------------------------------------
// Recurrence z_m = z_{m-1} @ A_w + u[:,m,:] @ B_w, fp32 exact.
// 256 blocks x 512 threads; block owns 8 batch rows. Thread t: out-col
// t&127, K-slice (t>>7)*32..+32 of A_w held in 32 registers (amortized over
// 8 rows x 64 steps). Cross-slice reduce via LDS.
// ---------------------------------------------------------------------------
__global__ __launch_bounds__(512) void recurrence_kernel(
    const float* __restrict__ zk, const float* __restrict__ u,
    const float* __restrict__ Bw, const float* __restrict__ Aw,
    float* __restrict__ zpred) {
    __shared__ float z_lds[8][128];
    __shared__ float part[4][8][128];
    __shared__ float Bw_lds[CDIM * 128];
    __shared__ float u_lds[8 * M_SEQ * CDIM];   // [b][m][c]
    const int tid   = threadIdx.x;
    const int lcol  = tid & 127;
    const int slice = tid >> 7;
    const int b0    = blockIdx.x * 8;

    float a[32];
    #pragma unroll
    for (int i = 0; i < 32; ++i) a[i] = Aw[(size_t)(slice * 32 + i) * 128 + lcol];

    for (int id = tid; id < 8 * 128; id += 512)
        z_lds[id >> 7][id & 127] = zk[(size_t)(b0 + (id >> 7)) * 128 + (id & 127)];
    for (int id = tid; id < CDIM * 128; id += 512) Bw_lds[id] = Bw[id];
    for (int id = tid; id < 8 * M_SEQ * CDIM; id += 512)
        u_lds[id] = u[(size_t)b0 * M_SEQ * CDIM + id];
    __syncthreads();

    for (int m = 0; m < M_SEQ; ++m) {
        #pragma unroll
        for (int b = 0; b < 8; ++b) {
            const float4* z4 = (const float4*)&z_lds[b][slice * 32];
            float s = 0.f;
            #pragma unroll
            for (int i = 0; i < 8; ++i) {
                float4 zv = z4[i];
                s += a[i * 4 + 0] * zv.x + a[i * 4 + 1] * zv.y +
                     a[i * 4 + 2] * zv.z + a[i * 4 + 3] * zv.w;
            }
            part[slice][b][lcol] = s;
        }
        __syncthreads();
        #pragma unroll
        for (int pass = 0; pass < 2; ++pass) {
            int id = tid + pass * 512;
            int b = id >> 7, l = id & 127;
            float v = part[0][b][l] + part[1][b][l] + part[2][b][l] + part[3][b][l];
            #pragma unroll
            for (int c = 0; c < CDIM; ++c)
                v += u_lds[(b * M_SEQ + m) * CDIM + c] * Bw_lds[c * 128 + l];
            zpred[((size_t)(b0 + b) * M_SEQ + m) * 128 + l] = v;
            z_lds[b][l] = v;
        }
        __syncthreads();
    }
}

// ---------------------------------------------------------------------------
// Decoder x_pred = z_pred @ C_w + C_b, fp32. 8 rows x 32 cols per 256-thr block.
// ---------------------------------------------------------------------------
__global__ __launch_bounds__(256) void decoder_kernel(
    const float* __restrict__ zpred, const float* __restrict__ Cw,
    const float* __restrict__ Cb, float* __restrict__ xpred) {
    __shared__ float C_lds[LDIM * SDIM];
    __shared__ float cb_lds[SDIM];
    const int tid = threadIdx.x;
    for (int id = tid; id < LDIM * SDIM; id += 256) C_lds[id] = Cw[id];
    if (tid < SDIM) cb_lds[tid] = Cb[tid];
    __syncthreads();

    const int col = tid & 31;
    const size_t row = (size_t)blockIdx.x * 8 + (tid >> 5);
    const float4* z4 = (const float4*)(zpred + row * LDIM);
    float s = cb_lds[col];
    #pragma unroll
    for (int i = 0; i < 32; ++i) {
        float4 zv = z4[i];
        s += zv.x * C_lds[(i * 4 + 0) * SDIM + col] + zv.y * C_lds[(i * 4 + 1) * SDIM + col] +
             zv.z * C_lds[(i * 4 + 2) * SDIM + col] + zv.w * C_lds[(i * 4 + 3) * SDIM + col];
    }
    xpred[row * SDIM + col] = s;
}

extern "C" void kernel_launch(void* const* d_in, const int* in_sizes, int n_in,
                              void* d_out, int out_size, void* d_ws, size_t ws_size,
                              hipStream_t stream) {
    const float* x_k    = (const float*)d_in[0];
    const float* u_seq  = (const float*)d_in[1];
    const float* x_next = (const float*)d_in[2];
    const float* w0 = (const float*)d_in[3];  const float* b0 = (const float*)d_in[4];
    const float* w1 = (const float*)d_in[5];  const float* b1 = (const float*)d_in[6];
    const float* w2 = (const float*)d_in[7];  const float* b2 = (const float*)d_in[8];
    const float* w3 = (const float*)d_in[9];  const float* b3 = (const float*)d_in[10];
    const float* A_w = (const float*)d_in[11];
    const float* B_w = (const float*)d_in[12];
    const float* C_w = (const float*)d_in[13];
    const float* C_b = (const float*)d_in[14];

    float* out    = (float*)d_out;
    float* z_pred = out;                                   // 2048*64*128
    float* x_pred = out + (size_t)NROWS_NEXT * LDIM;       // 2048*64*32
    float* z_tgt  = x_pred + (size_t)NROWS_NEXT * SDIM;    // 2048*64*128

    char* ws = (char*)d_ws;
    short* pw0 = (short*)(ws);                             // 32 KB
    short* pw1 = (short*)(ws + 32768);                     // 512 KB
    short* pw2 = (short*)(ws + 32768 + 524288);            // 512 KB
    short* pw3 = (short*)(ws + 32768 + 2 * 524288);        // 128 KB
    float* z_k_buf = (float*)(ws + 32768 + 2 * 524288 + 131072);  // 1 MB

    pack_weight<<<(SDIM * HDIM + 255) / 256, 256, 0, stream>>>(w0, pw0, SDIM, HDIM);
    pack_weight<<<(HDIM * HDIM + 255) / 256, 256, 0, stream>>>(w1, pw1, HDIM, HDIM);
    pack_weight<<<(HDIM * HDIM + 255) / 256, 256, 0, stream>>>(w2, pw2, HDIM, HDIM);
    pack_weight<<<(HDIM * LDIM + 255) / 256, 256, 0, stream>>>(w3, pw3, HDIM, LDIM);

    encoder_kernel<<<NROWS_ALL / 64, 512, 0, stream>>>(
        x_next, x_k, pw0, pw1, pw2, pw3, b0, b1, b2, b3, z_tgt, z_k_buf);

    recurrence_kernel<<<B_TOT / 8, 512, 0, stream>>>(z_k_buf, u_seq, B_w, A_w, z_pred);

    decoder_kernel<<<NROWS_NEXT / 8, 256, 0, stream>>>(z_pred, C_w, C_b, x_pred);
}

// Round 3
// 506.520 us; speedup vs baseline: 1.4580x; 1.4580x over previous
//
#include <hip/hip_runtime.h>

#define B_TOT 2048
#define M_SEQ 64
#define SDIM 32
#define CDIM 8
#define LDIM 128
#define HDIM 512

#define NROWS_NEXT (B_TOT * M_SEQ)       // 131072
#define NROWS_ALL  (NROWS_NEXT + B_TOT)  // 133120

typedef short bf16x8 __attribute__((ext_vector_type(8)));
typedef float f32x4  __attribute__((ext_vector_type(4)));

__device__ __forceinline__ unsigned short f2bf(float f) {
    unsigned int u = __builtin_bit_cast(unsigned int, f);
    u = u + 0x7FFFu + ((u >> 16) & 1u);   // round-to-nearest-even
    return (unsigned short)(u >> 16);
}

// XOR swizzle on LDS byte address for the bf16 h-buffer (1024B rows):
// flip bits 4-6 with row&7. Bijective, 16B-segment preserving.
// NOTE: must be applied to the FULL byte address (kt*64 occupies bit 6 —
// XOR-before-add carries into bit 7 and reads out of bounds; round-2 bug).
__device__ __forceinline__ unsigned int swz(unsigned int byte) {
    return byte ^ (((byte >> 10) & 7u) << 4);
}

// ---------------------------------------------------------------------------
// Pack fp32 weight W[K][N] into bf16 fragment-major layout for 16x16x32 MFMA.
// ---------------------------------------------------------------------------
__global__ void pack_weight(const float* __restrict__ W, short* __restrict__ out,
                            int K, int N) {
    int id = blockIdx.x * 256 + threadIdx.x;
    int total = K * N;
    if (id >= total) return;
    int j    = id & 7;
    int lane = (id >> 3) & 63;
    int tile = id >> 9;
    int NT   = N >> 4;
    int nt   = tile % NT;
    int kt   = tile / NT;
    int k = kt * 32 + ((lane >> 4) << 3) + j;
    int n = (nt << 4) + (lane & 15);
    out[id] = (short)f2bf(W[(size_t)k * N + n]);
}

// ---------------------------------------------------------------------------
// One MLP layer, 512 outputs, in-place in LDS. B-frags double-buffered
// (prefetch kt+1 while MFMAing kt) so L2 latency hides under compute.
// A-frag address: aoff = (base0 + kt*64) ^ xmask, then mt*16384 immediates
// (base0 + kt*64 < 16384, XOR is within bits 4-6 -> the mt add is carry-free).
// ---------------------------------------------------------------------------
__device__ __forceinline__ void layer_lds(char* hbuf, const short* __restrict__ pw,
                                          const float* __restrict__ bias,
                                          int ktCount, int wave, int lane) {
    const int l15 = lane & 15;
    const int lhi = lane >> 4;
    const unsigned base0 = (unsigned)(l15 * 1024 + (lhi << 4));
    const unsigned xmask = ((unsigned)(l15 & 7)) << 4;

    f32x4 acc[4][4];
    #pragma unroll
    for (int mt = 0; mt < 4; ++mt)
        #pragma unroll
        for (int nt = 0; nt < 4; ++nt)
            acc[mt][nt] = (f32x4){0.f, 0.f, 0.f, 0.f};

    const short* p = pw + (wave << 11) + (lane << 3);   // (wave*4 tiles)*512 + lane*8
    bf16x8 bcur[4];
    #pragma unroll
    for (int nt = 0; nt < 4; ++nt) bcur[nt] = *(const bf16x8*)(p + (nt << 9));

    for (int kt = 0; kt < ktCount; ++kt) {
        bf16x8 bnext[4];
        if (kt + 1 < ktCount) {
            const short* pn = p + 16384;                // next kt: 32 tiles * 512
            #pragma unroll
            for (int nt = 0; nt < 4; ++nt) bnext[nt] = *(const bf16x8*)(pn + (nt << 9));
        }
        const char* abase = hbuf + ((base0 + (unsigned)kt * 64u) ^ xmask);
        bf16x8 a[4];
        #pragma unroll
        for (int mt = 0; mt < 4; ++mt)
            a[mt] = *(const bf16x8*)(abase + mt * 16384);
        #pragma unroll
        for (int nt = 0; nt < 4; ++nt)
            #pragma unroll
            for (int mt = 0; mt < 4; ++mt)
                acc[mt][nt] = __builtin_amdgcn_mfma_f32_16x16x32_bf16(a[mt], bcur[nt], acc[mt][nt], 0, 0, 0);
        p += 16384;
        if (kt + 1 < ktCount) {
            #pragma unroll
            for (int nt = 0; nt < 4; ++nt) bcur[nt] = bnext[nt];
        }
    }
    __syncthreads();   // all reads of hbuf complete before in-place overwrite

    #pragma unroll
    for (int nt = 0; nt < 4; ++nt) {
        int colg = (wave * 4 + nt) * 16 + l15;
        float bv = bias[colg];
        #pragma unroll
        for (int mt = 0; mt < 4; ++mt) {
            #pragma unroll
            for (int r = 0; r < 4; ++r) {
                int row = mt * 16 + (lhi << 2) + r;
                float v = fmaxf(acc[mt][nt][r] + bv, 0.f);
                *(unsigned short*)(hbuf + swz((unsigned)(row * 1024 + colg * 2))) = f2bf(v);
            }
        }
    }
    __syncthreads();
}

// ---------------------------------------------------------------------------
// Fused encoder: rows [blk*64, blk*64+64). Blocks 0..2047 -> x_next rows,
// blocks 2048..2079 -> x_k rows.
// ---------------------------------------------------------------------------
__global__ __launch_bounds__(512, 4) void encoder_kernel(
    const float* __restrict__ x_next, const float* __restrict__ x_k,
    const short* __restrict__ pw0, const short* __restrict__ pw1,
    const short* __restrict__ pw2, const short* __restrict__ pw3,
    const float* __restrict__ b0, const float* __restrict__ b1,
    const float* __restrict__ b2, const float* __restrict__ b3,
    float* __restrict__ z_target, float* __restrict__ z_k_out) {
    __shared__ __attribute__((aligned(16))) char hbuf[64 * 1024];
    const int tid  = threadIdx.x;
    const int wave = tid >> 6;
    const int lane = tid & 63;
    const int l15  = lane & 15;
    const int lhi  = lane >> 4;
    const int r0   = blockIdx.x * 64;

    const float* xin;
    float* zout;
    if (r0 < NROWS_NEXT) {
        xin  = x_next + (size_t)r0 * SDIM;
        zout = z_target + (size_t)r0 * LDIM;
    } else {
        xin  = x_k + (size_t)(r0 - NROWS_NEXT) * SDIM;
        zout = z_k_out + (size_t)(r0 - NROWS_NEXT) * LDIM;
    }

    // stage 64x32 fp32 -> bf16 into h cols [0,32)
    {
        int row = tid >> 3;
        int c   = (tid & 7) * 4;
        float4 v = *(const float4*)(xin + row * SDIM + c);
        uint2 pk;
        pk.x = (unsigned int)f2bf(v.x) | ((unsigned int)f2bf(v.y) << 16);
        pk.y = (unsigned int)f2bf(v.z) | ((unsigned int)f2bf(v.w) << 16);
        *(uint2*)(hbuf + swz((unsigned)(row * 1024 + c * 2))) = pk;
    }
    __syncthreads();

    layer_lds(hbuf, pw0, b0, 1, wave, lane);    // 32  -> 512, relu
    layer_lds(hbuf, pw1, b1, 16, wave, lane);   // 512 -> 512, relu
    layer_lds(hbuf, pw2, b2, 16, wave, lane);   // 512 -> 512, relu

    // layer 3: 512 -> 128, no relu. Results staged fp32 in LDS, then fully
    // coalesced float4 global stores (the 64x128 fp32 tile is contiguous).
    {
        const unsigned base0 = (unsigned)(l15 * 1024 + (lhi << 4));
        const unsigned xmask = ((unsigned)(l15 & 7)) << 4;
        f32x4 acc[4];
        #pragma unroll
        for (int mt = 0; mt < 4; ++mt) acc[mt] = (f32x4){0.f, 0.f, 0.f, 0.f};

        const short* p = pw3 + (wave << 9) + (lane << 3);   // tile (kt*8+wave)
        bf16x8 bcur = *(const bf16x8*)(p);
        for (int kt = 0; kt < 16; ++kt) {
            bf16x8 bnext;
            if (kt < 15) bnext = *(const bf16x8*)(p + 4096);
            const char* abase = hbuf + ((base0 + (unsigned)kt * 64u) ^ xmask);
            bf16x8 a[4];
            #pragma unroll
            for (int mt = 0; mt < 4; ++mt)
                a[mt] = *(const bf16x8*)(abase + mt * 16384);
            #pragma unroll
            for (int mt = 0; mt < 4; ++mt)
                acc[mt] = __builtin_amdgcn_mfma_f32_16x16x32_bf16(a[mt], bcur, acc[mt], 0, 0, 0);
            p += 4096;
            if (kt < 15) bcur = bnext;
        }
        __syncthreads();   // done reading bf16 h; reuse hbuf as [64][128] fp32

        int colg = wave * 16 + l15;
        float bv = b3[colg];
        #pragma unroll
        for (int mt = 0; mt < 4; ++mt) {
            #pragma unroll
            for (int r = 0; r < 4; ++r) {
                int row = mt * 16 + (lhi << 2) + r;
                unsigned int byte = (unsigned)(row * 512 + colg * 4);
                byte ^= ((byte >> 9) & 7u) << 4;        // fp32-tile swizzle (512B rows)
                *(float*)(hbuf + byte) = acc[mt][r] + bv;
            }
        }
        __syncthreads();

        #pragma unroll
        for (int pass = 0; pass < 4; ++pass) {
            unsigned int L = (unsigned)(pass * 512 + tid) * 16;
            unsigned int A = L ^ (((L >> 9) & 7u) << 4);
            float4 v = *(const float4*)(hbuf + A);
            *(float4*)(zout + (L >> 2)) = v;
        }
    }
}

// ---------------------------------------------------------------------------
// Recurrence z_m = z_{m-1} @ A_w + u[:,m,:] @ B_w, fp32 exact.
// 512 blocks x 512 threads; block owns 4 batch rows (2 blocks/CU so barrier
// stalls overlap). Thread t: out-col t&127, K-slice (t>>7)*32 of A_w in regs.
// ---------------------------------------------------------------------------
#define RROWS 4
__global__ __launch_bounds__(512) void recurrence_kernel(
    const float* __restrict__ zk, const float* __restrict__ u,
    const float* __restrict__ Bw, const float* __restrict__ Aw,
    float* __restrict__ zpred) {
    __shared__ float z_lds[RROWS][128];
    __shared__ float part[4][RROWS][128];
    __shared__ float Bw_lds[CDIM * 128];
    __shared__ float u_lds[RROWS * M_SEQ * CDIM];   // [b][m][c]
    const int tid   = threadIdx.x;
    const int lcol  = tid & 127;
    const int slice = tid >> 7;
    const int b0    = blockIdx.x * RROWS;

    float a[32];
    #pragma unroll
    for (int i = 0; i < 32; ++i) a[i] = Aw[(size_t)(slice * 32 + i) * 128 + lcol];

    if (tid < RROWS * 128)
        z_lds[tid >> 7][tid & 127] = zk[(size_t)(b0 + (tid >> 7)) * 128 + (tid & 127)];
    for (int id = tid; id < CDIM * 128; id += 512) Bw_lds[id] = Bw[id];
    for (int id = tid; id < RROWS * M_SEQ * CDIM; id += 512)
        u_lds[id] = u[(size_t)b0 * M_SEQ * CDIM + id];
    __syncthreads();

    for (int m = 0; m < M_SEQ; ++m) {
        #pragma unroll
        for (int b = 0; b < RROWS; ++b) {
            const float4* z4 = (const float4*)&z_lds[b][slice * 32];
            float s = 0.f;
            #pragma unroll
            for (int i = 0; i < 8; ++i) {
                float4 zv = z4[i];
                s += a[i * 4 + 0] * zv.x + a[i * 4 + 1] * zv.y +
                     a[i * 4 + 2] * zv.z + a[i * 4 + 3] * zv.w;
            }
            part[slice][b][lcol] = s;
        }
        __syncthreads();
        {
            int b = tid >> 7, l = tid & 127;
            float v = part[0][b][l] + part[1][b][l] + part[2][b][l] + part[3][b][l];
            #pragma unroll
            for (int c = 0; c < CDIM; ++c)
                v += u_lds[(b * M_SEQ + m) * CDIM + c] * Bw_lds[c * 128 + l];
            zpred[((size_t)(b0 + b) * M_SEQ + m) * 128 + l] = v;
            z_lds[b][l] = v;
        }
        __syncthreads();
    }
}

// ---------------------------------------------------------------------------
// Decoder x_pred = z_pred @ C_w + C_b, fp32. 8 rows x 32 cols per 256-thr block.
// ---------------------------------------------------------------------------
__global__ __launch_bounds__(256) void decoder_kernel(
    const float* __restrict__ zpred, const float* __restrict__ Cw,
    const float* __restrict__ Cb, float* __restrict__ xpred) {
    __shared__ float C_lds[LDIM * SDIM];
    __shared__ float cb_lds[SDIM];
    const int tid = threadIdx.x;
    for (int id = tid; id < LDIM * SDIM; id += 256) C_lds[id] = Cw[id];
    if (tid < SDIM) cb_lds[tid] = Cb[tid];
    __syncthreads();

    const int col = tid & 31;
    const size_t row = (size_t)blockIdx.x * 8 + (tid >> 5);
    const float4* z4 = (const float4*)(zpred + row * LDIM);
    float s = cb_lds[col];
    #pragma unroll
    for (int i = 0; i < 32; ++i) {
        float4 zv = z4[i];
        s += zv.x * C_lds[(i * 4 + 0) * SDIM + col] + zv.y * C_lds[(i * 4 + 1) * SDIM + col] +
             zv.z * C_lds[(i * 4 + 2) * SDIM + col] + zv.w * C_lds[(i * 4 + 3) * SDIM + col];
    }
    xpred[row * SDIM + col] = s;
}

extern "C" void kernel_launch(void* const* d_in, const int* in_sizes, int n_in,
                              void* d_out, int out_size, void* d_ws, size_t ws_size,
                              hipStream_t stream) {
    const float* x_k    = (const float*)d_in[0];
    const float* u_seq  = (const float*)d_in[1];
    const float* x_next = (const float*)d_in[2];
    const float* w0 = (const float*)d_in[3];  const float* b0 = (const float*)d_in[4];
    const float* w1 = (const float*)d_in[5];  const float* b1 = (const float*)d_in[6];
    const float* w2 = (const float*)d_in[7];  const float* b2 = (const float*)d_in[8];
    const float* w3 = (const float*)d_in[9];  const float* b3 = (const float*)d_in[10];
    const float* A_w = (const float*)d_in[11];
    const float* B_w = (const float*)d_in[12];
    const float* C_w = (const float*)d_in[13];
    const float* C_b = (const float*)d_in[14];

    float* out    = (float*)d_out;
    float* z_pred = out;                                   // 2048*64*128
    float* x_pred = out + (size_t)NROWS_NEXT * LDIM;       // 2048*64*32
    float* z_tgt  = x_pred + (size_t)NROWS_NEXT * SDIM;    // 2048*64*128

    char* ws = (char*)d_ws;
    short* pw0 = (short*)(ws);                             // 32 KB
    short* pw1 = (short*)(ws + 32768);                     // 512 KB
    short* pw2 = (short*)(ws + 32768 + 524288);            // 512 KB
    short* pw3 = (short*)(ws + 32768 + 2 * 524288);        // 128 KB
    float* z_k_buf = (float*)(ws + 32768 + 2 * 524288 + 131072);  // 1 MB

    pack_weight<<<(SDIM * HDIM + 255) / 256, 256, 0, stream>>>(w0, pw0, SDIM, HDIM);
    pack_weight<<<(HDIM * HDIM + 255) / 256, 256, 0, stream>>>(w1, pw1, HDIM, HDIM);
    pack_weight<<<(HDIM * HDIM + 255) / 256, 256, 0, stream>>>(w2, pw2, HDIM, HDIM);
    pack_weight<<<(HDIM * LDIM + 255) / 256, 256, 0, stream>>>(w3, pw3, HDIM, LDIM);

    encoder_kernel<<<NROWS_ALL / 64, 512, 0, stream>>>(
        x_next, x_k, pw0, pw1, pw2, pw3, b0, b1, b2, b3, z_tgt, z_k_buf);

    recurrence_kernel<<<B_TOT / RROWS, 512, 0, stream>>>(z_k_buf, u_seq, B_w, A_w, z_pred);

    decoder_kernel<<<NROWS_NEXT / 8, 256, 0, stream>>>(z_pred, C_w, C_b, x_pred);
}